// Round 14
// baseline (687.561 us; speedup 1.0000x reference)
//
#include <hip/hip_runtime.h>
#include <cstdint>
#include <cstddef>

// -------- GCN 2-layer: out = A_norm @ prelu(A_norm @ (x W1) + b1) @ W2 + b2 --------
// A_norm = D^-1/2 (A + I) D^-1/2, deg = in-degree + 1 (PyG GCNConv default).
// edge_index arrives int32 [2][E]: src = ei[e], dst = ei[E + e].
//
// Round 14 = round 13 + staging-loop fix: 64-col tile needs 2048 bf16x8 units per
// plane; the loop only wrote 1024 (i<2) -> cols 32-63 of LDS uninitialized -> NaN.
// Now i<4.  Changes vs r12 otherwise identical:
//  * gemm1 drops the A-lo plane (r12 measured ZERO absmax change dropping H-lo ->
//    error pinned at Tp bf16 quantization floor). Both gemms 2-term Ah*(Bh+Bl).
//  * GEMM tile 64 cols: LDS 66 KB -> 2 blocks/CU; grid 784 blocks (3.06/CU).
// Aggregate (proven fabric-bound, 232us floor): one wave/node, 64-edge batched
// index loads + readlane broadcast, x8 ILP. CSR: bucketed 2-pass, packed 4B/edge.

#define IN_C 256
#define BSHIFT 9
#define BCAP 24576   // bucket capacity (avg ~16.3K edges/bucket; huge margin)

typedef __attribute__((ext_vector_type(8))) short bf16x8;
typedef __attribute__((ext_vector_type(4))) float f32x4;

__device__ __forceinline__ ushort f2bf(float x) {
    union { float f; uint32_t u; } v; v.f = x;
    uint32_t r = v.u + 0x7FFF + ((v.u >> 16) & 1);   // round-to-nearest-even
    return (ushort)(r >> 16);
}
__device__ __forceinline__ float bf2f(ushort b) {
    union { uint32_t u; float f; } v; v.u = ((uint32_t)b) << 16;
    return v.f;
}

// ---------------- CSR build: passA (bucket scatter, packed payload) ----------------
__global__ __launch_bounds__(256) void passA(const int* __restrict__ ei,
                                             int* __restrict__ bucketCnt,
                                             uint32_t* __restrict__ bucketBuf, int E, int NB) {
    __shared__ int hist[256];
    __shared__ int gbase[256];
    __shared__ int cur[256];
    int tid = threadIdx.x;
    hist[tid] = 0; cur[tid] = 0;
    __syncthreads();
    int e0 = blockIdx.x * 4096;
    int src_r[16], dst_r[16];
#pragma unroll
    for (int i = 0; i < 16; ++i) {
        int e = e0 + i * 256 + tid;
        if (e < E) {
            src_r[i] = ei[e];
            dst_r[i] = ei[(size_t)E + e];
            atomicAdd(&hist[dst_r[i] >> BSHIFT], 1);
        } else dst_r[i] = -1;
    }
    __syncthreads();
    if (tid < NB && hist[tid] > 0) gbase[tid] = atomicAdd(&bucketCnt[tid], hist[tid]);
    __syncthreads();
#pragma unroll
    for (int i = 0; i < 16; ++i) {
        if (dst_r[i] >= 0) {
            int b = dst_r[i] >> BSHIFT;
            int p = atomicAdd(&cur[b], 1);
            int pos = gbase[b] + p;
            if (pos < BCAP)
                bucketBuf[(size_t)b * BCAP + pos] =
                    (uint32_t)src_r[i] | ((uint32_t)(dst_r[i] & 511) << 17);
        }
    }
}

// ---------------- CSR build: bucket base scan (one 256-thread LDS scan) ----------------
__global__ __launch_bounds__(256) void bucket_scanP(const int* __restrict__ bucketCnt,
                                                    int* __restrict__ bucket_base,
                                                    int* __restrict__ row_ptr, int NB, int N) {
    __shared__ int sdata[256];
    int tid = threadIdx.x;
    int c = 0;
    if (tid < NB) { c = bucketCnt[tid]; if (c > BCAP) c = BCAP; }
    sdata[tid] = c;
    __syncthreads();
    for (int o = 1; o < 256; o <<= 1) {
        int add = (tid >= o) ? sdata[tid - o] : 0;
        __syncthreads();
        sdata[tid] += add;
        __syncthreads();
    }
    if (tid < NB) bucket_base[tid] = sdata[tid] - c;
    if (tid == 255) row_ptr[N] = sdata[255];
}

// ------- CSR build: passB (one block per bucket; local CSR in LDS; writes dis) -------
__global__ __launch_bounds__(256) void passB(const uint32_t* __restrict__ bucketBuf,
                                             const int* __restrict__ bucketCnt,
                                             const int* __restrict__ bucket_base,
                                             int* __restrict__ row_ptr,
                                             int* __restrict__ csr_src,
                                             float* __restrict__ dis, int N) {
    __shared__ int cnt[512];
    __shared__ int ofs[512];
    __shared__ int ssum[256];
    int b = blockIdx.x, tid = threadIdx.x;
    int base_node = b << BSHIFT;
    int nnodes = N - base_node; if (nnodes > 512) nnodes = 512;
    int nE = bucketCnt[b]; if (nE > BCAP) nE = BCAP;
    const uint32_t* buf = bucketBuf + (size_t)b * BCAP;
    cnt[tid] = 0; cnt[tid + 256] = 0;
    __syncthreads();
    for (int i = tid; i < nE; i += 256) {
        atomicAdd(&cnt[buf[i] >> 17], 1);
    }
    __syncthreads();
    int c0 = cnt[2 * tid], c1 = cnt[2 * tid + 1];
    int s = c0 + c1;
    ssum[tid] = s;
    __syncthreads();
    for (int o = 1; o < 256; o <<= 1) {
        int add = (tid >= o) ? ssum[tid - o] : 0;
        __syncthreads();
        ssum[tid] += add;
        __syncthreads();
    }
    int run = ssum[tid] - s;           // exclusive within bucket
    int gb = bucket_base[b];
    int o0 = gb + run, o1 = gb + run + c0;
    ofs[2 * tid] = o0; ofs[2 * tid + 1] = o1;
    if (2 * tid < nnodes) {
        row_ptr[base_node + 2 * tid] = o0;
        dis[base_node + 2 * tid] = rsqrtf((float)(c0 + 1));
    }
    if (2 * tid + 1 < nnodes) {
        row_ptr[base_node + 2 * tid + 1] = o1;
        dis[base_node + 2 * tid + 1] = rsqrtf((float)(c1 + 1));
    }
    __syncthreads();
    for (int i = tid; i < nE; i += 256) {
        uint32_t p = buf[i];
        int pos = atomicAdd(&ofs[p >> 17], 1);
        csr_src[pos] = (int)(p & 0x1FFFF);
    }
}

// ------- weight prep (both layers, one launch): W[k][n] f32 -> WT[n][k] hi/lo bf16 -------
__global__ __launch_bounds__(256) void prep_w2(const float* __restrict__ W1,
                                               const float* __restrict__ W2,
                                               ushort* __restrict__ W1h, ushort* __restrict__ W1l,
                                               ushort* __restrict__ W2h, ushort* __restrict__ W2l) {
    int id = blockIdx.x * 256 + threadIdx.x;   // 131072
    const float* W = (id < 65536) ? W1 : W2;
    ushort* Th = (id < 65536) ? W1h : W2h;
    ushort* Tl = (id < 65536) ? W1l : W2l;
    int lid = id & 65535;
    int n = lid >> 8, k = lid & 255;
    float w = W[k * 256 + n];
    ushort h = f2bf(w);
    Th[lid] = h;
    Tl[lid] = f2bf(w - bf2f(h));
}

// ------- LDS-B MFMA GEMM core geometry (both layers) -------
// Block: 512 thr (8 waves), tile 512 rows x 64 cols. LDS 66 KB (2 blocks/CU).
// Per-wave 64x64 = 4x4 16x16 frags. W hi/lo staged; A-side single bf16 plane.
// Staging: 2048 bf16x8 units per plane / 512 thr = 4 iterations (both planes inside).
// gemm_f32a: A fp32 from global, converted in-register (hi only).
__global__ __launch_bounds__(512, 2) void gemm_f32a(const float* __restrict__ A,
                                                    const ushort* __restrict__ Bh,
                                                    const ushort* __restrict__ Bl,
                                                    const float* __restrict__ dis,
                                                    ushort* __restrict__ C, int M) {
    __shared__ ushort Bsh[64][264];
    __shared__ ushort Bsl[64][264];
    int tid = threadIdx.x;
    int col0 = (blockIdx.x & 3) << 6;
    int brow = (blockIdx.x >> 2) << 9;
#pragma unroll
    for (int i = 0; i < 4; ++i) {
        int u = tid + i * 512;          // 2048 units per plane
        int cb = u >> 5, ko = (u & 31) * 8;
        *(bf16x8*)&Bsh[cb][ko] = *(const bf16x8*)&Bh[(size_t)(col0 + cb) * 256 + ko];
        *(bf16x8*)&Bsl[cb][ko] = *(const bf16x8*)&Bl[(size_t)(col0 + cb) * 256 + ko];
    }
    __syncthreads();

    int wave = tid >> 6, lane = tid & 63;
    int row0 = brow + wave * 64;
    if (row0 >= M) return;
    int lrow = lane & 15, lk = (lane >> 4) * 8;

    f32x4 acc[4][4];
#pragma unroll
    for (int i = 0; i < 4; ++i)
#pragma unroll
        for (int j = 0; j < 4; ++j) acc[i][j] = (f32x4)0.f;

#pragma unroll
    for (int ks = 0; ks < 8; ++ks) {
        int kb = ks * 32 + lk;
        bf16x8 ah[4];
#pragma unroll
        for (int i = 0; i < 4; ++i) {
            int row = row0 + i * 16 + lrow;
            if (row < M) {
                float4 f0 = *(const float4*)&A[(size_t)row * 256 + kb];
                float4 f1 = *(const float4*)&A[(size_t)row * 256 + kb + 4];
                float f[8] = {f0.x, f0.y, f0.z, f0.w, f1.x, f1.y, f1.z, f1.w};
#pragma unroll
                for (int k = 0; k < 8; ++k) ah[i][k] = (short)f2bf(f[k]);
            } else {
                ah[i] = (bf16x8)(short)0;
            }
        }
#pragma unroll
        for (int j = 0; j < 4; ++j) {
            bf16x8 bh = *(bf16x8*)&Bsh[j * 16 + lrow][kb];
            bf16x8 bl = *(bf16x8*)&Bsl[j * 16 + lrow][kb];
#pragma unroll
            for (int i = 0; i < 4; ++i) {
                acc[i][j] = __builtin_amdgcn_mfma_f32_16x16x32_bf16(ah[i], bh, acc[i][j], 0, 0, 0);
                acc[i][j] = __builtin_amdgcn_mfma_f32_16x16x32_bf16(ah[i], bl, acc[i][j], 0, 0, 0);
            }
        }
    }
    int rb = (lane >> 4) * 4;
#pragma unroll
    for (int i = 0; i < 4; ++i) {
#pragma unroll
        for (int r = 0; r < 4; ++r) {
            int row = row0 + i * 16 + rb + r;
            if (row >= M) continue;
            float dr = dis[row];
#pragma unroll
            for (int j = 0; j < 4; ++j) {
                int col = col0 + j * 16 + lrow;
                C[(size_t)row * 256 + col] = f2bf(dr * acc[i][j][r]);
            }
        }
    }
}

// gemm_h: A bf16 single plane from global.
__global__ __launch_bounds__(512, 2) void gemm_h(const ushort* __restrict__ Ah,
                                                 const ushort* __restrict__ Bh,
                                                 const ushort* __restrict__ Bl,
                                                 const float* __restrict__ dis,
                                                 ushort* __restrict__ C, int M) {
    __shared__ ushort Bsh[64][264];
    __shared__ ushort Bsl[64][264];
    int tid = threadIdx.x;
    int col0 = (blockIdx.x & 3) << 6;
    int brow = (blockIdx.x >> 2) << 9;
#pragma unroll
    for (int i = 0; i < 4; ++i) {
        int u = tid + i * 512;          // 2048 units per plane
        int cb = u >> 5, ko = (u & 31) * 8;
        *(bf16x8*)&Bsh[cb][ko] = *(const bf16x8*)&Bh[(size_t)(col0 + cb) * 256 + ko];
        *(bf16x8*)&Bsl[cb][ko] = *(const bf16x8*)&Bl[(size_t)(col0 + cb) * 256 + ko];
    }
    __syncthreads();

    int wave = tid >> 6, lane = tid & 63;
    int row0 = brow + wave * 64;
    if (row0 >= M) return;
    int lrow = lane & 15, lk = (lane >> 4) * 8;

    f32x4 acc[4][4];
#pragma unroll
    for (int i = 0; i < 4; ++i)
#pragma unroll
        for (int j = 0; j < 4; ++j) acc[i][j] = (f32x4)0.f;

#pragma unroll
    for (int ks = 0; ks < 8; ++ks) {
        int kb = ks * 32 + lk;
        bf16x8 ah[4];
#pragma unroll
        for (int i = 0; i < 4; ++i) {
            int row = row0 + i * 16 + lrow;
            ah[i] = (row < M) ? *(const bf16x8*)&Ah[(size_t)row * 256 + kb]
                              : (bf16x8)(short)0;
        }
#pragma unroll
        for (int j = 0; j < 4; ++j) {
            bf16x8 bh = *(bf16x8*)&Bsh[j * 16 + lrow][kb];
            bf16x8 bl = *(bf16x8*)&Bsl[j * 16 + lrow][kb];
#pragma unroll
            for (int i = 0; i < 4; ++i) {
                acc[i][j] = __builtin_amdgcn_mfma_f32_16x16x32_bf16(ah[i], bh, acc[i][j], 0, 0, 0);
                acc[i][j] = __builtin_amdgcn_mfma_f32_16x16x32_bf16(ah[i], bl, acc[i][j], 0, 0, 0);
            }
        }
    }
    int rb = (lane >> 4) * 4;
#pragma unroll
    for (int i = 0; i < 4; ++i) {
#pragma unroll
        for (int r = 0; r < 4; ++r) {
            int row = row0 + i * 16 + rb + r;
            if (row >= M) continue;
            float dr = dis[row];
#pragma unroll
            for (int j = 0; j < 4; ++j) {
                int col = col0 + j * 16 + lrow;
                C[(size_t)row * 256 + col] = f2bf(dr * acc[i][j][r]);
            }
        }
    }
}

// ---------------- aggregate: out[n] = dis[n]*(T'[n] + sum_e T'[src_e]) + b ----------------
// one wave per node; 64-edge batched index loads + readlane broadcast, x8 ILP.
// mode 1: PReLU + bf16 hi plane only. mode 0: fp32 nontemporal.
__global__ __launch_bounds__(256) void aggregate8(const ushort* __restrict__ Tp,
                                                  const int* __restrict__ row_ptr,
                                                  const int* __restrict__ csr_src,
                                                  const float* __restrict__ dis,
                                                  const float* __restrict__ bias,
                                                  const float* __restrict__ alpha_p,
                                                  float* __restrict__ outf,
                                                  ushort* __restrict__ outh,
                                                  int N, int mode) {
    int wave = threadIdx.x >> 6;
    int lane = threadIdx.x & 63;
    int n = blockIdx.x * 4 + wave;
    if (n >= N) return;
    int c = lane * 4;

    float ax[8], ay[8], az[8], aw[8];
#pragma unroll
    for (int t = 0; t < 8; ++t) { ax[t] = 0.f; ay[t] = 0.f; az[t] = 0.f; aw[t] = 0.f; }
    {
        ushort4 sv = *(const ushort4*)&Tp[(size_t)n * 256 + c];
        ax[0] = bf2f(sv.x); ay[0] = bf2f(sv.y); az[0] = bf2f(sv.z); aw[0] = bf2f(sv.w);
    }

    int e0 = row_ptr[n], e1 = row_ptr[n + 1];
    for (int base = e0; base < e1; base += 64) {
        int rem = e1 - base;
        int m = rem < 64 ? rem : 64;
        int idx = csr_src[base + (lane < m ? lane : 0)];
        int j = 0;
        for (; j + 8 <= m; j += 8) {
            int s[8];
            ushort4 v[8];
#pragma unroll
            for (int t = 0; t < 8; ++t) s[t] = __builtin_amdgcn_readlane(idx, j + t);
#pragma unroll
            for (int t = 0; t < 8; ++t) v[t] = *(const ushort4*)&Tp[(size_t)s[t] * 256 + c];
#pragma unroll
            for (int t = 0; t < 8; ++t) {
                ax[t] += bf2f(v[t].x); ay[t] += bf2f(v[t].y);
                az[t] += bf2f(v[t].z); aw[t] += bf2f(v[t].w);
            }
        }
        for (; j < m; ++j) {
            int s = __builtin_amdgcn_readlane(idx, j);
            ushort4 v = *(const ushort4*)&Tp[(size_t)s * 256 + c];
            ax[0] += bf2f(v.x); ay[0] += bf2f(v.y); az[0] += bf2f(v.z); aw[0] += bf2f(v.w);
        }
    }
#pragma unroll
    for (int t = 1; t < 8; ++t) { ax[0] += ax[t]; ay[0] += ay[t]; az[0] += az[t]; aw[0] += aw[t]; }

    float dn = dis[n];
    float4 bv = *(const float4*)&bias[c];
    float rx = dn * ax[0] + bv.x;
    float ry = dn * ay[0] + bv.y;
    float rz = dn * az[0] + bv.z;
    float rw = dn * aw[0] + bv.w;
    if (mode) {
        float al = *alpha_p;
        rx = rx >= 0.f ? rx : al * rx;
        ry = ry >= 0.f ? ry : al * ry;
        rz = rz >= 0.f ? rz : al * rz;
        rw = rw >= 0.f ? rw : al * rw;
        *(ushort4*)&outh[(size_t)n * 256 + c] =
            make_ushort4(f2bf(rx), f2bf(ry), f2bf(rz), f2bf(rw));
    } else {
        f32x4 r; r.x = rx; r.y = ry; r.z = rz; r.w = rw;
        __builtin_nontemporal_store(r, (f32x4*)&outf[(size_t)n * 256 + c]);
    }
}

extern "C" void kernel_launch(void* const* d_in, const int* in_sizes, int n_in,
                              void* d_out, int out_size, void* d_ws, size_t ws_size,
                              hipStream_t stream) {
    const float* x = (const float*)d_in[0];
    const int* ei = (const int*)d_in[1];          // int32 (harness converts int64 -> int32)
    const float* W1 = (const float*)d_in[2];
    const float* b1 = (const float*)d_in[3];
    const float* W2 = (const float*)d_in[4];
    const float* b2 = (const float*)d_in[5];
    const float* alpha = (const float*)d_in[6];
    int N = in_sizes[0] / IN_C;
    int E = in_sizes[1] / 2;
    int NB = (N + 511) >> BSHIFT;
    if (NB > 256 || N > 131072) return;            // packed src needs 17 bits

    // ---- workspace layout (~65 MB) ----
    char* ws = (char*)d_ws;
    size_t off = 0;
    auto alloc = [&](size_t bytes) {
        void* p = ws + off;
        off = (off + bytes + 255) & ~(size_t)255;
        return p;
    };
    int* row_ptr     = (int*)alloc(((size_t)N + 1) * 4);
    float* dis       = (float*)alloc((size_t)N * 4);
    int* csr_src     = (int*)alloc((size_t)E * 4);
    int* bucketCnt   = (int*)alloc(256 * 4);
    int* bucket_base = (int*)alloc(256 * 4);
    ushort* Tp       = (ushort*)alloc((size_t)N * IN_C * 2);   // 51.2 MB (bucketBuf alias)
    if (off > ws_size) return;                     // clean fail if ws too small
    uint32_t* bucketBuf = (uint32_t*)Tp;           // dead before gemm1 writes Tp
    if ((size_t)NB * BCAP * 4 > (size_t)N * IN_C * 2) return;  // alias capacity guard

    // ---- d_out doubles as scratch (dead before final write) ----
    char* dob = (char*)d_out;
    ushort* Hh  = (ushort*)dob;
    ushort* W1h = (ushort*)(dob + (size_t)N * IN_C * 2);
    ushort* W1l = W1h + 65536;
    ushort* W2h = W1h + 131072;
    ushort* W2l = W1h + 196608;
    float* outf = (float*)d_out;

    hipMemsetAsync(bucketCnt, 0, 256 * 4, stream);

    // ---- CSR build (bucketed; passB also writes dis) ----
    passA<<<(E + 4095) / 4096, 256, 0, stream>>>(ei, bucketCnt, bucketBuf, E, NB);
    bucket_scanP<<<1, 256, 0, stream>>>(bucketCnt, bucket_base, row_ptr, NB, N);
    passB<<<NB, 256, 0, stream>>>(bucketBuf, bucketCnt, bucket_base, row_ptr, csr_src, dis, N);

    // ---- weight prep (single launch for both layers) ----
    prep_w2<<<512, 256, 0, stream>>>(W1, W2, W1h, W1l, W2h, W2l);

    int gblocks = ((N + 511) / 512) * 4;
    int ablocks = (N + 3) / 4;

    // layer 1: T' = dis * (x@W1)  (x fp32 -> bf16 in-register, 2-term);  H(bf16) = prelu(...)
    gemm_f32a<<<gblocks, 512, 0, stream>>>(x, W1h, W1l, dis, Tp, N);
    aggregate8<<<ablocks, 256, 0, stream>>>(Tp, row_ptr, csr_src, dis, b1, alpha,
                                            nullptr, Hh, N, 1);
    // layer 2: T' = dis * (H@W2) (2-term);  out = dn*(T'n + sum T's) + b2
    gemm_h<<<gblocks, 512, 0, stream>>>(Hh, W2h, W2l, dis, Tp, N);
    aggregate8<<<ablocks, 256, 0, stream>>>(Tp, row_ptr, csr_src, dis, b2, alpha,
                                            outf, nullptr, N, 0);
}

// Round 15
// 630.264 us; speedup vs baseline: 1.0909x; 1.0909x over previous
//
#include <hip/hip_runtime.h>
#include <cstdint>
#include <cstddef>

// -------- GCN 2-layer: out = A_norm @ prelu(A_norm @ (x W1) + b1) @ W2 + b2 --------
// A_norm = D^-1/2 (A + I) D^-1/2, deg = in-degree + 1 (PyG GCNConv default).
// edge_index arrives int32 [2][E]: src = ei[e], dst = ei[E + e].
//
// Round 15: revert to 128-col tile (r14's 64-col quadrupled A re-reads, +38us),
// and drop W-lo entirely -> 1-term MFMA. Evidence: THREE independent lo-plane
// drops (H-lo r12, x-lo r14) each changed absmax by ZERO (pinned at 1.95e-3 =
// 1 ULP of the bf16 Tp quantization); W rounding is the same per-term 2^-9
// mechanism averaged over K=256. LDS halves to 66 KB -> 2 blocks/CU and the
// 392-block grid fits one scheduling wave (no tail).
// Aggregate (proven fabric-bound, 231us floor): one wave/node, 64-edge batched
// index loads + readlane broadcast, x8 ILP. CSR: bucketed 2-pass, packed 4B/edge.

#define IN_C 256
#define BSHIFT 9
#define BCAP 24576   // bucket capacity (avg ~16.3K edges/bucket; huge margin)

typedef __attribute__((ext_vector_type(8))) short bf16x8;
typedef __attribute__((ext_vector_type(4))) float f32x4;

__device__ __forceinline__ ushort f2bf(float x) {
    union { float f; uint32_t u; } v; v.f = x;
    uint32_t r = v.u + 0x7FFF + ((v.u >> 16) & 1);   // round-to-nearest-even
    return (ushort)(r >> 16);
}
__device__ __forceinline__ float bf2f(ushort b) {
    union { uint32_t u; float f; } v; v.u = ((uint32_t)b) << 16;
    return v.f;
}

// ---------------- CSR build: passA (bucket scatter, packed payload) ----------------
__global__ __launch_bounds__(256) void passA(const int* __restrict__ ei,
                                             int* __restrict__ bucketCnt,
                                             uint32_t* __restrict__ bucketBuf, int E, int NB) {
    __shared__ int hist[256];
    __shared__ int gbase[256];
    __shared__ int cur[256];
    int tid = threadIdx.x;
    hist[tid] = 0; cur[tid] = 0;
    __syncthreads();
    int e0 = blockIdx.x * 4096;
    int src_r[16], dst_r[16];
#pragma unroll
    for (int i = 0; i < 16; ++i) {
        int e = e0 + i * 256 + tid;
        if (e < E) {
            src_r[i] = ei[e];
            dst_r[i] = ei[(size_t)E + e];
            atomicAdd(&hist[dst_r[i] >> BSHIFT], 1);
        } else dst_r[i] = -1;
    }
    __syncthreads();
    if (tid < NB && hist[tid] > 0) gbase[tid] = atomicAdd(&bucketCnt[tid], hist[tid]);
    __syncthreads();
#pragma unroll
    for (int i = 0; i < 16; ++i) {
        if (dst_r[i] >= 0) {
            int b = dst_r[i] >> BSHIFT;
            int p = atomicAdd(&cur[b], 1);
            int pos = gbase[b] + p;
            if (pos < BCAP)
                bucketBuf[(size_t)b * BCAP + pos] =
                    (uint32_t)src_r[i] | ((uint32_t)(dst_r[i] & 511) << 17);
        }
    }
}

// ---------------- CSR build: bucket base scan (one 256-thread LDS scan) ----------------
__global__ __launch_bounds__(256) void bucket_scanP(const int* __restrict__ bucketCnt,
                                                    int* __restrict__ bucket_base,
                                                    int* __restrict__ row_ptr, int NB, int N) {
    __shared__ int sdata[256];
    int tid = threadIdx.x;
    int c = 0;
    if (tid < NB) { c = bucketCnt[tid]; if (c > BCAP) c = BCAP; }
    sdata[tid] = c;
    __syncthreads();
    for (int o = 1; o < 256; o <<= 1) {
        int add = (tid >= o) ? sdata[tid - o] : 0;
        __syncthreads();
        sdata[tid] += add;
        __syncthreads();
    }
    if (tid < NB) bucket_base[tid] = sdata[tid] - c;
    if (tid == 255) row_ptr[N] = sdata[255];
}

// ------- CSR build: passB (one block per bucket; local CSR in LDS; writes dis) -------
__global__ __launch_bounds__(256) void passB(const uint32_t* __restrict__ bucketBuf,
                                             const int* __restrict__ bucketCnt,
                                             const int* __restrict__ bucket_base,
                                             int* __restrict__ row_ptr,
                                             int* __restrict__ csr_src,
                                             float* __restrict__ dis, int N) {
    __shared__ int cnt[512];
    __shared__ int ofs[512];
    __shared__ int ssum[256];
    int b = blockIdx.x, tid = threadIdx.x;
    int base_node = b << BSHIFT;
    int nnodes = N - base_node; if (nnodes > 512) nnodes = 512;
    int nE = bucketCnt[b]; if (nE > BCAP) nE = BCAP;
    const uint32_t* buf = bucketBuf + (size_t)b * BCAP;
    cnt[tid] = 0; cnt[tid + 256] = 0;
    __syncthreads();
    for (int i = tid; i < nE; i += 256) {
        atomicAdd(&cnt[buf[i] >> 17], 1);
    }
    __syncthreads();
    int c0 = cnt[2 * tid], c1 = cnt[2 * tid + 1];
    int s = c0 + c1;
    ssum[tid] = s;
    __syncthreads();
    for (int o = 1; o < 256; o <<= 1) {
        int add = (tid >= o) ? ssum[tid - o] : 0;
        __syncthreads();
        ssum[tid] += add;
        __syncthreads();
    }
    int run = ssum[tid] - s;           // exclusive within bucket
    int gb = bucket_base[b];
    int o0 = gb + run, o1 = gb + run + c0;
    ofs[2 * tid] = o0; ofs[2 * tid + 1] = o1;
    if (2 * tid < nnodes) {
        row_ptr[base_node + 2 * tid] = o0;
        dis[base_node + 2 * tid] = rsqrtf((float)(c0 + 1));
    }
    if (2 * tid + 1 < nnodes) {
        row_ptr[base_node + 2 * tid + 1] = o1;
        dis[base_node + 2 * tid + 1] = rsqrtf((float)(c1 + 1));
    }
    __syncthreads();
    for (int i = tid; i < nE; i += 256) {
        uint32_t p = buf[i];
        int pos = atomicAdd(&ofs[p >> 17], 1);
        csr_src[pos] = (int)(p & 0x1FFFF);
    }
}

// ------- weight prep (both layers, one launch): W[k][n] f32 -> WT[n][k] bf16 (hi only) -------
__global__ __launch_bounds__(256) void prep_w2(const float* __restrict__ W1,
                                               const float* __restrict__ W2,
                                               ushort* __restrict__ W1h,
                                               ushort* __restrict__ W2h) {
    int id = blockIdx.x * 256 + threadIdx.x;   // 131072
    const float* W = (id < 65536) ? W1 : W2;
    ushort* Th = (id < 65536) ? W1h : W2h;
    int lid = id & 65535;
    int n = lid >> 8, k = lid & 255;
    Th[lid] = f2bf(W[k * 256 + n]);
}

// ------- LDS-B MFMA GEMM core geometry (both layers) -------
// Block: 512 thr (8 waves), tile 512 rows x 128 cols. LDS 66 KB (2 blocks/CU);
// 392-block grid fits one scheduling wave. Per-wave 64x128 = 4x8 16x16 frags.
// W single bf16 plane -> 1 MFMA term. A read 2x total (two col-blocks per row).
// gemm_f32a: A fp32 from global, converted in-register.
__global__ __launch_bounds__(512, 2) void gemm_f32a(const float* __restrict__ A,
                                                    const ushort* __restrict__ Bh,
                                                    const float* __restrict__ dis,
                                                    ushort* __restrict__ C, int M) {
    __shared__ ushort Bsh[128][264];
    int tid = threadIdx.x;
    int col0 = (blockIdx.x & 1) << 7;
    int brow = (blockIdx.x >> 1) << 9;
    // stage B: 128 cols x 256 k; 4096 bf16x8 units / 512 thr = 8 iters
#pragma unroll
    for (int i = 0; i < 8; ++i) {
        int u = tid + i * 512;
        int cb = u >> 5, ko = (u & 31) * 8;
        *(bf16x8*)&Bsh[cb][ko] = *(const bf16x8*)&Bh[(size_t)(col0 + cb) * 256 + ko];
    }
    __syncthreads();

    int wave = tid >> 6, lane = tid & 63;
    int row0 = brow + wave * 64;
    if (row0 >= M) return;
    int lrow = lane & 15, lk = (lane >> 4) * 8;

    f32x4 acc[4][8];
#pragma unroll
    for (int i = 0; i < 4; ++i)
#pragma unroll
        for (int j = 0; j < 8; ++j) acc[i][j] = (f32x4)0.f;

#pragma unroll
    for (int ks = 0; ks < 8; ++ks) {
        int kb = ks * 32 + lk;
        bf16x8 ah[4];
#pragma unroll
        for (int i = 0; i < 4; ++i) {
            int row = row0 + i * 16 + lrow;
            if (row < M) {
                float4 f0 = *(const float4*)&A[(size_t)row * 256 + kb];
                float4 f1 = *(const float4*)&A[(size_t)row * 256 + kb + 4];
                float f[8] = {f0.x, f0.y, f0.z, f0.w, f1.x, f1.y, f1.z, f1.w};
#pragma unroll
                for (int k = 0; k < 8; ++k) ah[i][k] = (short)f2bf(f[k]);
            } else {
                ah[i] = (bf16x8)(short)0;
            }
        }
#pragma unroll
        for (int j = 0; j < 8; ++j) {
            bf16x8 bh = *(bf16x8*)&Bsh[j * 16 + lrow][kb];
#pragma unroll
            for (int i = 0; i < 4; ++i)
                acc[i][j] = __builtin_amdgcn_mfma_f32_16x16x32_bf16(ah[i], bh, acc[i][j], 0, 0, 0);
        }
    }
    int rb = (lane >> 4) * 4;
#pragma unroll
    for (int i = 0; i < 4; ++i) {
#pragma unroll
        for (int r = 0; r < 4; ++r) {
            int row = row0 + i * 16 + rb + r;
            if (row >= M) continue;
            float dr = dis[row];
#pragma unroll
            for (int j = 0; j < 8; ++j) {
                int col = col0 + j * 16 + lrow;
                C[(size_t)row * 256 + col] = f2bf(dr * acc[i][j][r]);
            }
        }
    }
}

// gemm_h: A bf16 single plane from global.
__global__ __launch_bounds__(512, 2) void gemm_h(const ushort* __restrict__ Ah,
                                                 const ushort* __restrict__ Bh,
                                                 const float* __restrict__ dis,
                                                 ushort* __restrict__ C, int M) {
    __shared__ ushort Bsh[128][264];
    int tid = threadIdx.x;
    int col0 = (blockIdx.x & 1) << 7;
    int brow = (blockIdx.x >> 1) << 9;
#pragma unroll
    for (int i = 0; i < 8; ++i) {
        int u = tid + i * 512;
        int cb = u >> 5, ko = (u & 31) * 8;
        *(bf16x8*)&Bsh[cb][ko] = *(const bf16x8*)&Bh[(size_t)(col0 + cb) * 256 + ko];
    }
    __syncthreads();

    int wave = tid >> 6, lane = tid & 63;
    int row0 = brow + wave * 64;
    if (row0 >= M) return;
    int lrow = lane & 15, lk = (lane >> 4) * 8;

    f32x4 acc[4][8];
#pragma unroll
    for (int i = 0; i < 4; ++i)
#pragma unroll
        for (int j = 0; j < 8; ++j) acc[i][j] = (f32x4)0.f;

#pragma unroll
    for (int ks = 0; ks < 8; ++ks) {
        int kb = ks * 32 + lk;
        bf16x8 ah[4];
#pragma unroll
        for (int i = 0; i < 4; ++i) {
            int row = row0 + i * 16 + lrow;
            ah[i] = (row < M) ? *(const bf16x8*)&Ah[(size_t)row * 256 + kb]
                              : (bf16x8)(short)0;
        }
#pragma unroll
        for (int j = 0; j < 8; ++j) {
            bf16x8 bh = *(bf16x8*)&Bsh[j * 16 + lrow][kb];
#pragma unroll
            for (int i = 0; i < 4; ++i)
                acc[i][j] = __builtin_amdgcn_mfma_f32_16x16x32_bf16(ah[i], bh, acc[i][j], 0, 0, 0);
        }
    }
    int rb = (lane >> 4) * 4;
#pragma unroll
    for (int i = 0; i < 4; ++i) {
#pragma unroll
        for (int r = 0; r < 4; ++r) {
            int row = row0 + i * 16 + rb + r;
            if (row >= M) continue;
            float dr = dis[row];
#pragma unroll
            for (int j = 0; j < 8; ++j) {
                int col = col0 + j * 16 + lrow;
                C[(size_t)row * 256 + col] = f2bf(dr * acc[i][j][r]);
            }
        }
    }
}

// ---------------- aggregate: out[n] = dis[n]*(T'[n] + sum_e T'[src_e]) + b ----------------
// one wave per node; 64-edge batched index loads + readlane broadcast, x8 ILP.
// mode 1: PReLU + bf16 hi plane only. mode 0: fp32 nontemporal.
__global__ __launch_bounds__(256) void aggregate8(const ushort* __restrict__ Tp,
                                                  const int* __restrict__ row_ptr,
                                                  const int* __restrict__ csr_src,
                                                  const float* __restrict__ dis,
                                                  const float* __restrict__ bias,
                                                  const float* __restrict__ alpha_p,
                                                  float* __restrict__ outf,
                                                  ushort* __restrict__ outh,
                                                  int N, int mode) {
    int wave = threadIdx.x >> 6;
    int lane = threadIdx.x & 63;
    int n = blockIdx.x * 4 + wave;
    if (n >= N) return;
    int c = lane * 4;

    float ax[8], ay[8], az[8], aw[8];
#pragma unroll
    for (int t = 0; t < 8; ++t) { ax[t] = 0.f; ay[t] = 0.f; az[t] = 0.f; aw[t] = 0.f; }
    {
        ushort4 sv = *(const ushort4*)&Tp[(size_t)n * 256 + c];
        ax[0] = bf2f(sv.x); ay[0] = bf2f(sv.y); az[0] = bf2f(sv.z); aw[0] = bf2f(sv.w);
    }

    int e0 = row_ptr[n], e1 = row_ptr[n + 1];
    for (int base = e0; base < e1; base += 64) {
        int rem = e1 - base;
        int m = rem < 64 ? rem : 64;
        int idx = csr_src[base + (lane < m ? lane : 0)];
        int j = 0;
        for (; j + 8 <= m; j += 8) {
            int s[8];
            ushort4 v[8];
#pragma unroll
            for (int t = 0; t < 8; ++t) s[t] = __builtin_amdgcn_readlane(idx, j + t);
#pragma unroll
            for (int t = 0; t < 8; ++t) v[t] = *(const ushort4*)&Tp[(size_t)s[t] * 256 + c];
#pragma unroll
            for (int t = 0; t < 8; ++t) {
                ax[t] += bf2f(v[t].x); ay[t] += bf2f(v[t].y);
                az[t] += bf2f(v[t].z); aw[t] += bf2f(v[t].w);
            }
        }
        for (; j < m; ++j) {
            int s = __builtin_amdgcn_readlane(idx, j);
            ushort4 v = *(const ushort4*)&Tp[(size_t)s * 256 + c];
            ax[0] += bf2f(v.x); ay[0] += bf2f(v.y); az[0] += bf2f(v.z); aw[0] += bf2f(v.w);
        }
    }
#pragma unroll
    for (int t = 1; t < 8; ++t) { ax[0] += ax[t]; ay[0] += ay[t]; az[0] += az[t]; aw[0] += aw[t]; }

    float dn = dis[n];
    float4 bv = *(const float4*)&bias[c];
    float rx = dn * ax[0] + bv.x;
    float ry = dn * ay[0] + bv.y;
    float rz = dn * az[0] + bv.z;
    float rw = dn * aw[0] + bv.w;
    if (mode) {
        float al = *alpha_p;
        rx = rx >= 0.f ? rx : al * rx;
        ry = ry >= 0.f ? ry : al * ry;
        rz = rz >= 0.f ? rz : al * rz;
        rw = rw >= 0.f ? rw : al * rw;
        *(ushort4*)&outh[(size_t)n * 256 + c] =
            make_ushort4(f2bf(rx), f2bf(ry), f2bf(rz), f2bf(rw));
    } else {
        f32x4 r; r.x = rx; r.y = ry; r.z = rz; r.w = rw;
        __builtin_nontemporal_store(r, (f32x4*)&outf[(size_t)n * 256 + c]);
    }
}

extern "C" void kernel_launch(void* const* d_in, const int* in_sizes, int n_in,
                              void* d_out, int out_size, void* d_ws, size_t ws_size,
                              hipStream_t stream) {
    const float* x = (const float*)d_in[0];
    const int* ei = (const int*)d_in[1];          // int32 (harness converts int64 -> int32)
    const float* W1 = (const float*)d_in[2];
    const float* b1 = (const float*)d_in[3];
    const float* W2 = (const float*)d_in[4];
    const float* b2 = (const float*)d_in[5];
    const float* alpha = (const float*)d_in[6];
    int N = in_sizes[0] / IN_C;
    int E = in_sizes[1] / 2;
    int NB = (N + 511) >> BSHIFT;
    if (NB > 256 || N > 131072) return;            // packed src needs 17 bits

    // ---- workspace layout (~65 MB) ----
    char* ws = (char*)d_ws;
    size_t off = 0;
    auto alloc = [&](size_t bytes) {
        void* p = ws + off;
        off = (off + bytes + 255) & ~(size_t)255;
        return p;
    };
    int* row_ptr     = (int*)alloc(((size_t)N + 1) * 4);
    float* dis       = (float*)alloc((size_t)N * 4);
    int* csr_src     = (int*)alloc((size_t)E * 4);
    int* bucketCnt   = (int*)alloc(256 * 4);
    int* bucket_base = (int*)alloc(256 * 4);
    ushort* Tp       = (ushort*)alloc((size_t)N * IN_C * 2);   // 51.2 MB (bucketBuf alias)
    if (off > ws_size) return;                     // clean fail if ws too small
    uint32_t* bucketBuf = (uint32_t*)Tp;           // dead before gemm1 writes Tp
    if ((size_t)NB * BCAP * 4 > (size_t)N * IN_C * 2) return;  // alias capacity guard

    // ---- d_out doubles as scratch (dead before final write) ----
    char* dob = (char*)d_out;
    ushort* Hh  = (ushort*)dob;
    ushort* W1h = (ushort*)(dob + (size_t)N * IN_C * 2);
    ushort* W2h = W1h + 65536;
    float* outf = (float*)d_out;

    hipMemsetAsync(bucketCnt, 0, 256 * 4, stream);

    // ---- CSR build (bucketed; passB also writes dis) ----
    passA<<<(E + 4095) / 4096, 256, 0, stream>>>(ei, bucketCnt, bucketBuf, E, NB);
    bucket_scanP<<<1, 256, 0, stream>>>(bucketCnt, bucket_base, row_ptr, NB, N);
    passB<<<NB, 256, 0, stream>>>(bucketBuf, bucketCnt, bucket_base, row_ptr, csr_src, dis, N);

    // ---- weight prep (single launch for both layers, hi only) ----
    prep_w2<<<512, 256, 0, stream>>>(W1, W2, W1h, W2h);

    int gblocks = ((N + 511) / 512) * 2;
    int ablocks = (N + 3) / 4;

    // layer 1: T' = dis * (x@W1)  (x fp32 -> bf16 in-register, 1-term);  H(bf16) = prelu(...)
    gemm_f32a<<<gblocks, 512, 0, stream>>>(x, W1h, dis, Tp, N);
    aggregate8<<<ablocks, 256, 0, stream>>>(Tp, row_ptr, csr_src, dis, b1, alpha,
                                            nullptr, Hh, N, 1);
    // layer 2: T' = dis * (H@W2) (1-term);  out = dn*(T'n + sum T's) + b2
    gemm_h<<<gblocks, 512, 0, stream>>>(Hh, W2h, dis, Tp, N);
    aggregate8<<<ablocks, 256, 0, stream>>>(Tp, row_ptr, csr_src, dis, b2, alpha,
                                            outf, nullptr, N, 0);
}